// Round 3
// baseline (6944.334 us; speedup 1.0000x reference)
//
#include <hip/hip_runtime.h>
#include <math.h>

#define N_NODES 40960
#define N_EDGES 655360
#define NPG     640
#define NGRAPH  64
#define DH      128
#define NLAYERS 4
#define GATE_EPS 1e-6f
#define BN_EPS   1e-5f

// Static device scratch pool: allocated at module load (graph-capture safe).
// ws_size proved < 509 MB in rounds 1-2; we stop using d_ws entirely.
#define POOL_BYTES 531000000ull
__device__ __attribute__((aligned(256))) unsigned char g_pool[POOL_BYTES];

static __device__ __forceinline__ float sigmoidf_(float x) {
  return 1.f / (1.f + __expf(-x));
}

// bf16 helpers (RNE)
static __device__ __forceinline__ unsigned short f2bf(float f) {
  unsigned int u = __float_as_uint(f);
  unsigned int r = 0x7FFFu + ((u >> 16) & 1u);
  return (unsigned short)((u + r) >> 16);
}
static __device__ __forceinline__ float bf2f(unsigned short h) {
  return __uint_as_float(((unsigned int)h) << 16);
}

// ---------------------------------------------------------------------------
// fp32 GEMM: out[M,128] = concat(Xa[M,Ka], Xb[M,Kb]) @ W[Ka+Kb,128] + bias
// MODE 0: plain store. MODE 2: no store; per-graph mean into hg.
// Block 256 threads, tile 64 rows x 128 cols, BK=16.
// ---------------------------------------------------------------------------
template <int MODE>
__global__ __launch_bounds__(256)
void gemm_k(const float* __restrict__ Xa, int Ka,
            const float* __restrict__ Xb, int Kb,
            const float* __restrict__ W,
            const float* __restrict__ bias,
            float* __restrict__ out,
            float* __restrict__ hg, float inv_nodes, int npg)
{
  __shared__ float Xs[16][68];
  __shared__ float Ws[16][128];
  __shared__ float red[8][128];

  const int t  = threadIdx.x;
  const int ty = t >> 5;
  const int tx = t & 31;
  const int row0 = blockIdx.x * 64;
  const int K = Ka + Kb;

  float acc[8][4];
#pragma unroll
  for (int i = 0; i < 8; ++i)
#pragma unroll
    for (int j = 0; j < 4; ++j) acc[i][j] = 0.f;

  const int xr = t >> 2;
  const int xk = (t & 3) << 2;
  const int wr = t >> 5;
  const int wc = tx << 2;

  for (int kk = 0; kk < K; kk += 16) {
    const float* xbase; int ldk, kloc;
    if (kk < Ka) { xbase = Xa; ldk = Ka; kloc = kk; }
    else         { xbase = Xb; ldk = Kb; kloc = kk - Ka; }
    float4 xv = *reinterpret_cast<const float4*>(
        &xbase[(size_t)(row0 + xr) * ldk + kloc + xk]);
    Xs[xk + 0][xr] = xv.x; Xs[xk + 1][xr] = xv.y;
    Xs[xk + 2][xr] = xv.z; Xs[xk + 3][xr] = xv.w;

    float4 wv0 = *reinterpret_cast<const float4*>(&W[(size_t)(kk + wr) * 128 + wc]);
    float4 wv1 = *reinterpret_cast<const float4*>(&W[(size_t)(kk + wr + 8) * 128 + wc]);
    *reinterpret_cast<float4*>(&Ws[wr][wc])     = wv0;
    *reinterpret_cast<float4*>(&Ws[wr + 8][wc]) = wv1;
    __syncthreads();

#pragma unroll
    for (int k = 0; k < 16; ++k) {
      float4 b4 = *reinterpret_cast<const float4*>(&Ws[k][wc]);
      float4 a0 = *reinterpret_cast<const float4*>(&Xs[k][ty << 3]);
      float4 a1 = *reinterpret_cast<const float4*>(&Xs[k][(ty << 3) + 4]);
      float a[8] = {a0.x, a0.y, a0.z, a0.w, a1.x, a1.y, a1.z, a1.w};
      float b[4] = {b4.x, b4.y, b4.z, b4.w};
#pragma unroll
      for (int i = 0; i < 8; ++i) {
        acc[i][0] += a[i] * b[0];
        acc[i][1] += a[i] * b[1];
        acc[i][2] += a[i] * b[2];
        acc[i][3] += a[i] * b[3];
      }
    }
    __syncthreads();
  }

  float4 bb = *reinterpret_cast<const float4*>(&bias[wc]);
  float bv[4] = {bb.x, bb.y, bb.z, bb.w};

  if (MODE == 0) {
#pragma unroll
    for (int i = 0; i < 8; ++i) {
      int r = row0 + (ty << 3) + i;
      float4 ov;
      ov.x = acc[i][0] + bv[0]; ov.y = acc[i][1] + bv[1];
      ov.z = acc[i][2] + bv[2]; ov.w = acc[i][3] + bv[3];
      *reinterpret_cast<float4*>(&out[(size_t)r * 128 + wc]) = ov;
    }
  } else {  // MODE 2: per-graph mean accumulate
    float csum[4] = {0, 0, 0, 0};
#pragma unroll
    for (int i = 0; i < 8; ++i) {
      csum[0] += acc[i][0]; csum[1] += acc[i][1];
      csum[2] += acc[i][2]; csum[3] += acc[i][3];
    }
#pragma unroll
    for (int j = 0; j < 4; ++j) red[ty][wc + j] = csum[j];
    __syncthreads();
    if (ty == 0) {
      int g = row0 / npg;
#pragma unroll
      for (int j = 0; j < 4; ++j) {
        float s = 0;
#pragma unroll
        for (int q = 0; q < 8; ++q) s += red[q][wc + j];
        atomicAdd(&hg[(size_t)g * 128 + wc + j], (s + 64.f * bv[j]) * inv_nodes);
      }
    }
  }
}

// ---------------------------------------------------------------------------
// Edge-gate GEMM (bf16 in/out): hat[e,:] = bf16( ef@B3 + b3 + B1h[src] + B2h[dst] )
// plus column sum/sumsq of the rounded value into stats[0:128]/[128:256].
// ---------------------------------------------------------------------------
__global__ __launch_bounds__(256)
void gemm_edge_gate(const unsigned short* __restrict__ ef,
                    const float* __restrict__ W, const float* __restrict__ bias,
                    unsigned short* __restrict__ hat,
                    const int* __restrict__ srcI, const int* __restrict__ dstI,
                    const float* __restrict__ G1, const float* __restrict__ G2,
                    float* __restrict__ stats)
{
  __shared__ float Xs[16][68];
  __shared__ float Ws[16][128];
  __shared__ float red[8][128];

  const int t  = threadIdx.x;
  const int ty = t >> 5;
  const int tx = t & 31;
  const int row0 = blockIdx.x * 64;

  float acc[8][4];
#pragma unroll
  for (int i = 0; i < 8; ++i)
#pragma unroll
    for (int j = 0; j < 4; ++j) acc[i][j] = 0.f;

  const int xr = t >> 2;
  const int xk = (t & 3) << 2;
  const int wr = t >> 5;
  const int wc = tx << 2;

  for (int kk = 0; kk < 128; kk += 16) {
    ushort4 xv = *reinterpret_cast<const ushort4*>(
        &ef[(size_t)(row0 + xr) * 128 + kk + xk]);
    Xs[xk + 0][xr] = bf2f(xv.x); Xs[xk + 1][xr] = bf2f(xv.y);
    Xs[xk + 2][xr] = bf2f(xv.z); Xs[xk + 3][xr] = bf2f(xv.w);

    float4 wv0 = *reinterpret_cast<const float4*>(&W[(size_t)(kk + wr) * 128 + wc]);
    float4 wv1 = *reinterpret_cast<const float4*>(&W[(size_t)(kk + wr + 8) * 128 + wc]);
    *reinterpret_cast<float4*>(&Ws[wr][wc])     = wv0;
    *reinterpret_cast<float4*>(&Ws[wr + 8][wc]) = wv1;
    __syncthreads();

#pragma unroll
    for (int k = 0; k < 16; ++k) {
      float4 b4 = *reinterpret_cast<const float4*>(&Ws[k][wc]);
      float4 a0 = *reinterpret_cast<const float4*>(&Xs[k][ty << 3]);
      float4 a1 = *reinterpret_cast<const float4*>(&Xs[k][(ty << 3) + 4]);
      float a[8] = {a0.x, a0.y, a0.z, a0.w, a1.x, a1.y, a1.z, a1.w};
      float b[4] = {b4.x, b4.y, b4.z, b4.w};
#pragma unroll
      for (int i = 0; i < 8; ++i) {
        acc[i][0] += a[i] * b[0];
        acc[i][1] += a[i] * b[1];
        acc[i][2] += a[i] * b[2];
        acc[i][3] += a[i] * b[3];
      }
    }
    __syncthreads();
  }

  float4 bb = *reinterpret_cast<const float4*>(&bias[wc]);
  float bv[4] = {bb.x, bb.y, bb.z, bb.w};

  float csum[4] = {0, 0, 0, 0}, csq[4] = {0, 0, 0, 0};
#pragma unroll
  for (int i = 0; i < 8; ++i) {
    int e = row0 + (ty << 3) + i;
    int s = srcI[e], d = dstI[e];
    float4 g1 = *reinterpret_cast<const float4*>(&G1[(size_t)s * 128 + wc]);
    float4 g2 = *reinterpret_cast<const float4*>(&G2[(size_t)d * 128 + wc]);
    ushort4 ov;
    ov.x = f2bf(acc[i][0] + bv[0] + g1.x + g2.x);
    ov.y = f2bf(acc[i][1] + bv[1] + g1.y + g2.y);
    ov.z = f2bf(acc[i][2] + bv[2] + g1.z + g2.z);
    ov.w = f2bf(acc[i][3] + bv[3] + g1.w + g2.w);
    *reinterpret_cast<ushort4*>(&hat[(size_t)e * 128 + wc]) = ov;
    float v0 = bf2f(ov.x), v1 = bf2f(ov.y), v2 = bf2f(ov.z), v3 = bf2f(ov.w);
    csum[0] += v0; csum[1] += v1; csum[2] += v2; csum[3] += v3;
    csq[0] += v0 * v0; csq[1] += v1 * v1; csq[2] += v2 * v2; csq[3] += v3 * v3;
  }
#pragma unroll
  for (int j = 0; j < 4; ++j) red[ty][wc + j] = csum[j];
  __syncthreads();
  if (ty == 0) {
#pragma unroll
    for (int j = 0; j < 4; ++j) {
      float s = 0;
#pragma unroll
      for (int q = 0; q < 8; ++q) s += red[q][wc + j];
      atomicAdd(&stats[wc + j], s);
    }
  }
  __syncthreads();
#pragma unroll
  for (int j = 0; j < 4; ++j) red[ty][wc + j] = csq[j];
  __syncthreads();
  if (ty == 0) {
#pragma unroll
    for (int j = 0; j < 4; ++j) {
      float s = 0;
#pragma unroll
      for (int q = 0; q < 8; ++q) s += red[q][wc + j];
      atomicAdd(&stats[128 + wc + j], s);
    }
  }
}

// ---------------------------------------------------------------------------
__global__ void embed_nodes_k(const int* __restrict__ idx, const float* __restrict__ table,
                              float* __restrict__ out, int M)
{
  int t = blockIdx.x * 256 + threadIdx.x;
  if (t < M * 32) {
    int r = t >> 5, c = t & 31;
    reinterpret_cast<float4*>(out)[t] =
        reinterpret_cast<const float4*>(table)[idx[r] * 32 + c];
  }
}

__global__ void embed_edges_bf(const int* __restrict__ idx, const float* __restrict__ table,
                               unsigned short* __restrict__ out, int M)
{
  int t = blockIdx.x * 256 + threadIdx.x;
  if (t < M * 32) {
    int r = t >> 5, c = t & 31;
    float4 v = reinterpret_cast<const float4*>(table)[idx[r] * 32 + c];
    ushort4 o;
    o.x = f2bf(v.x); o.y = f2bf(v.y); o.z = f2bf(v.z); o.w = f2bf(v.w);
    reinterpret_cast<ushort4*>(out)[t] = o;
  }
}

// ---------------------------------------------------------------------------
// CSR build over dst
// ---------------------------------------------------------------------------
__global__ void hist_k(const int* __restrict__ dstI, int* __restrict__ deg, int E)
{
  int e = blockIdx.x * 256 + threadIdx.x;
  if (e < E) atomicAdd(&deg[dstI[e]], 1);
}

__global__ void scan_k(const int* __restrict__ deg, int* __restrict__ row_start,
                       int* __restrict__ cursor, int n)
{
  __shared__ int buf[1024];
  __shared__ int carry;
  int t = threadIdx.x;
  if (t == 0) carry = 0;
  __syncthreads();
  for (int b0 = 0; b0 < n; b0 += 1024) {
    int v = (b0 + t < n) ? deg[b0 + t] : 0;
    buf[t] = v;
    __syncthreads();
    for (int off = 1; off < 1024; off <<= 1) {
      int add = (t >= off) ? buf[t - off] : 0;
      __syncthreads();
      buf[t] += add;
      __syncthreads();
    }
    int incl = buf[t];
    int excl = carry + incl - v;
    if (b0 + t < n) { row_start[b0 + t] = excl; cursor[b0 + t] = excl; }
    __syncthreads();
    if (t == 1023) carry += incl;
    __syncthreads();
  }
  if (t == 0) row_start[n] = carry;
}

__global__ void fill_k(const int* __restrict__ dstI, int* __restrict__ cursor,
                       int* __restrict__ eidx, int E)
{
  int e = blockIdx.x * 256 + threadIdx.x;
  if (e < E) {
    int p = atomicAdd(&cursor[dstI[e]], 1);
    eidx[p] = e;
  }
}

// ---------------------------------------------------------------------------
// Per-node gate normalization + aggregation (CSR over dst), hat in bf16.
// ---------------------------------------------------------------------------
__global__ __launch_bounds__(128)
void gate_agg(const unsigned short* __restrict__ hat, const int* __restrict__ row_start,
              const int* __restrict__ eidx, const int* __restrict__ srcI,
              const float* __restrict__ A1hp, const float* __restrict__ A2hp,
              const float* __restrict__ C1p, const float* __restrict__ C2p,
              float* __restrict__ hraw, float* __restrict__ pc)
{
  int n = blockIdx.x;
  int d = threadIdx.x;
  int beg = row_start[n], end = row_start[n + 1];
  float ssum = 0.f;
  for (int ii = beg; ii < end; ++ii) {
    int e = eidx[ii];
    ssum += sigmoidf_(bf2f(hat[(size_t)e * 128 + d]));
  }
  float inv = 1.f / (ssum + GATE_EPS);
  float ha = 0.f, pa = 0.f;
  for (int ii = beg; ii < end; ++ii) {
    int e = eidx[ii];
    int s = srcI[e];
    float eta = sigmoidf_(bf2f(hat[(size_t)e * 128 + d])) * inv;
    ha += eta * A2hp[(size_t)s * 128 + d];
    pa += eta * C2p[(size_t)s * 128 + d];
  }
  size_t ix = (size_t)n * 128 + d;
  hraw[ix] = A1hp[ix] + ha;
  pc[ix] += tanhf(C1p[ix] + pa);
}

// ---------------------------------------------------------------------------
__global__ __launch_bounds__(128)
void col_stats(const float* __restrict__ x, float* __restrict__ stats, int rowsPerBlock)
{
  int d = threadIdx.x;
  size_t r0 = (size_t)blockIdx.x * rowsPerBlock;
  float s = 0.f, q = 0.f;
  for (int i = 0; i < rowsPerBlock; ++i) {
    float v = x[(r0 + i) * 128 + d];
    s += v; q += v * v;
  }
  atomicAdd(&stats[d], s);
  atomicAdd(&stats[128 + d], q);
}

// BN stats -> per-channel scale (ss[0:128]) and shift (ss[128:256])
__global__ void bn_finalize(const float* __restrict__ stats, const float* __restrict__ g,
                            const float* __restrict__ b, float invM, float* __restrict__ ss)
{
  int c = threadIdx.x;
  float m = stats[c] * invM;
  float v = stats[128 + c] * invM - m * m;
  float A = rsqrtf(v + BN_EPS) * g[c];
  ss[c] = A;
  ss[128 + c] = b[c] - m * A;
}

// dest[i] += relu(x*A + B), fp32, total4 = M*32 float4 groups
__global__ void apply_bn_relu_res_f32(float* __restrict__ dest, const float* __restrict__ xraw,
                                      const float* __restrict__ ss, int total4)
{
  int t = blockIdx.x * 256 + threadIdx.x;
  if (t >= total4) return;
  int c4 = t & 31;
  float4 x = reinterpret_cast<const float4*>(xraw)[t];
  float4 A = reinterpret_cast<const float4*>(ss)[c4];
  float4 B = reinterpret_cast<const float4*>(ss + 128)[c4];
  float4 dv = reinterpret_cast<float4*>(dest)[t];
  dv.x += fmaxf(x.x * A.x + B.x, 0.f);
  dv.y += fmaxf(x.y * A.y + B.y, 0.f);
  dv.z += fmaxf(x.z * A.z + B.z, 0.f);
  dv.w += fmaxf(x.w * A.w + B.w, 0.f);
  reinterpret_cast<float4*>(dest)[t] = dv;
}

// ef[i] = bf16( ef[i] + relu(hat[i]*A + B) ), 8 bf16 per thread, total8 = E*16
__global__ void apply_bn_relu_res_bf(unsigned short* __restrict__ ef,
                                     const unsigned short* __restrict__ hat,
                                     const float* __restrict__ ss, int total8)
{
  int t = blockIdx.x * 256 + threadIdx.x;
  if (t >= total8) return;
  int c8 = t & 15;
  uint4 xb = reinterpret_cast<const uint4*>(hat)[t];
  uint4 eb = reinterpret_cast<const uint4*>(ef)[t];
  float4 A0 = reinterpret_cast<const float4*>(ss)[c8 * 2];
  float4 A1 = reinterpret_cast<const float4*>(ss)[c8 * 2 + 1];
  float4 B0 = reinterpret_cast<const float4*>(ss + 128)[c8 * 2];
  float4 B1 = reinterpret_cast<const float4*>(ss + 128)[c8 * 2 + 1];
  float Av[8] = {A0.x, A0.y, A0.z, A0.w, A1.x, A1.y, A1.z, A1.w};
  float Bv[8] = {B0.x, B0.y, B0.z, B0.w, B1.x, B1.y, B1.z, B1.w};
  unsigned int xw[4] = {xb.x, xb.y, xb.z, xb.w};
  unsigned int ew[4] = {eb.x, eb.y, eb.z, eb.w};
  uint4 ov;
  unsigned int res[4];
#pragma unroll
  for (int i = 0; i < 4; ++i) {
    float xlo = bf2f((unsigned short)(xw[i] & 0xffffu));
    float xhi = bf2f((unsigned short)(xw[i] >> 16));
    float elo = bf2f((unsigned short)(ew[i] & 0xffffu));
    float ehi = bf2f((unsigned short)(ew[i] >> 16));
    float ylo = elo + fmaxf(xlo * Av[2 * i] + Bv[2 * i], 0.f);
    float yhi = ehi + fmaxf(xhi * Av[2 * i + 1] + Bv[2 * i + 1], 0.f);
    res[i] = (unsigned int)f2bf(ylo) | ((unsigned int)f2bf(yhi) << 16);
  }
  ov.x = res[0]; ov.y = res[1]; ov.z = res[2]; ov.w = res[3];
  reinterpret_cast<uint4*>(ef)[t] = ov;
}

// ---------------------------------------------------------------------------
__global__ __launch_bounds__(256)
void po_gemm(const float* __restrict__ pc, const float* __restrict__ w,
             const float* __restrict__ b, float* __restrict__ po)
{
  __shared__ float pcs[16][128];
  __shared__ float wl[128][16];
  int t = threadIdx.x;
  int n0 = blockIdx.x * 16;
  for (int i = t; i < 512; i += 256) {
    int r = i >> 5, c = (i & 31) << 2;
    *reinterpret_cast<float4*>(&pcs[r][c]) =
        *reinterpret_cast<const float4*>(&pc[(size_t)(n0 + r) * 128 + c]);
  }
  for (int i = t; i < 512; i += 256) {
    int r = i >> 2, c = (i & 3) << 2;
    *reinterpret_cast<float4*>(&wl[r][c]) =
        *reinterpret_cast<const float4*>(&w[r * 16 + c]);
  }
  __syncthreads();
  int i = t >> 4, j = t & 15;
  float acc = b[j];
  for (int k = 0; k < 128; ++k) acc += pcs[i][k] * wl[k][j];
  po[(size_t)(n0 + i) * 16 + j] = acc;
}

__global__ __launch_bounds__(256)
void pe_norm(float* __restrict__ po)
{
  int g = blockIdx.x;
  int t = threadIdx.x;
  int j = t & 15, grp = t >> 4;
  __shared__ float red[16][16];
  __shared__ float mean_s[16];
  __shared__ float nrm_s[16];
  size_t bse = (size_t)g * NPG * 16;
  float s = 0.f;
  for (int i = grp; i < NPG; i += 16) s += po[bse + i * 16 + j];
  red[grp][j] = s;
  __syncthreads();
  if (grp == 0) {
    float m = 0.f;
    for (int q = 0; q < 16; ++q) m += red[q][j];
    mean_s[j] = m / NPG;
  }
  __syncthreads();
  float m = mean_s[j];
  float q2 = 0.f;
  for (int i = grp; i < NPG; i += 16) {
    float c = po[bse + i * 16 + j] - m;
    q2 += c * c;
  }
  red[grp][j] = q2;
  __syncthreads();
  if (grp == 0) {
    float v = 0.f;
    for (int q = 0; q < 16; ++q) v += red[q][j];
    nrm_s[j] = sqrtf(v);
  }
  __syncthreads();
  float inv = 1.f / nrm_s[j];
  for (int i = grp; i < NPG; i += 16) {
    size_t ix = bse + i * 16 + j;
    po[ix] = (po[ix] - m) * inv;
  }
}

__global__ __launch_bounds__(256)
void mlp_head(const float* __restrict__ hg,
              const float* __restrict__ w0, const float* __restrict__ b0,
              const float* __restrict__ w1, const float* __restrict__ b1,
              const float* __restrict__ w2, const float* __restrict__ b2,
              float* __restrict__ out)
{
  __shared__ float hs[64 * 128];
  __shared__ float y0[64 * 64];
  __shared__ float y1[64 * 32];
  int t = threadIdx.x;
  for (int i = t; i < 64 * 128 / 4; i += 256)
    reinterpret_cast<float4*>(hs)[i] = reinterpret_cast<const float4*>(hg)[i];
  __syncthreads();
  for (int o = t; o < 64 * 64; o += 256) {
    int i = o >> 6, j = o & 63;
    float a = b0[j];
    for (int k = 0; k < 128; ++k) a += hs[i * 128 + k] * w0[k * 64 + j];
    y0[o] = fmaxf(a, 0.f);
  }
  __syncthreads();
  for (int o = t; o < 64 * 32; o += 256) {
    int i = o >> 5, j = o & 31;
    float a = b1[j];
    for (int k = 0; k < 64; ++k) a += y0[i * 64 + k] * w1[k * 32 + j];
    y1[o] = fmaxf(a, 0.f);
  }
  __syncthreads();
  if (t < 64) {
    float a = b2[0];
    for (int k = 0; k < 32; ++k) a += y1[t * 32 + k] * w2[k];
    out[t] = a;
  }
}

__global__ void fill_sentinel(float* out, int n, float v)
{
  int t = blockIdx.x * 256 + threadIdx.x;
  if (t < n) out[t] = v;
}

// ---------------------------------------------------------------------------
extern "C" void kernel_launch(void* const* d_in, const int* in_sizes, int n_in,
                              void* d_out, int out_size, void* d_ws, size_t ws_size,
                              hipStream_t stream)
{
  const int*   h_atoms = (const int*)d_in[0];
  const int*   e_bonds = (const int*)d_in[1];
  const int*   srcI    = (const int*)d_in[2];
  const int*   dstI    = (const int*)d_in[3];
  const float* p_in    = (const float*)d_in[5];
  const float* W_emb_h = (const float*)d_in[6];
  const float* W_emb_p = (const float*)d_in[7];
  const float* b_emb_p = (const float*)d_in[8];
  const float* W_emb_e = (const float*)d_in[9];
  const float* A1_w = (const float*)d_in[10];
  const float* A1_b = (const float*)d_in[11];
  const float* A2_w = (const float*)d_in[12];
  const float* A2_b = (const float*)d_in[13];
  const float* B1_w = (const float*)d_in[14];
  const float* B1_b = (const float*)d_in[15];
  const float* B2_w = (const float*)d_in[16];
  const float* B2_b = (const float*)d_in[17];
  const float* B3_w = (const float*)d_in[18];
  const float* B3_b = (const float*)d_in[19];
  const float* C1_w = (const float*)d_in[20];
  const float* C1_b = (const float*)d_in[21];
  const float* C2_w = (const float*)d_in[22];
  const float* C2_b = (const float*)d_in[23];
  const float* bn_h_g = (const float*)d_in[24];
  const float* bn_h_b = (const float*)d_in[25];
  const float* bn_e_g = (const float*)d_in[26];
  const float* bn_e_b = (const float*)d_in[27];
  const float* p_out_w = (const float*)d_in[28];
  const float* p_out_b = (const float*)d_in[29];
  const float* Whp_w   = (const float*)d_in[30];
  const float* Whp_b   = (const float*)d_in[31];
  const float* mlp_w0  = (const float*)d_in[32];
  const float* mlp_b0  = (const float*)d_in[33];
  const float* mlp_w1  = (const float*)d_in[34];
  const float* mlp_b1  = (const float*)d_in[35];
  const float* mlp_w2  = (const float*)d_in[36];
  const float* mlp_b2  = (const float*)d_in[37];

  // ---- static pool (cached address; first call is pre-capture) ----
  static void* pool_ptr = nullptr;
  if (!pool_ptr) {
    if (hipGetSymbolAddress(&pool_ptr, HIP_SYMBOL(g_pool)) != hipSuccess || !pool_ptr) {
      fill_sentinel<<<dim3(1), dim3(256), 0, stream>>>((float*)d_out, out_size, 12345.0f);
      return;
    }
  }

  float* fbase = (float*)pool_ptr;
  size_t fo = 0;
  auto carvef = [&](size_t nf) { float* r = fbase + fo; fo += nf; return r; };
  float* h    = carvef((size_t)N_NODES * DH);
  float* pc   = carvef((size_t)N_NODES * DH);
  float* B1h  = carvef((size_t)N_NODES * DH);
  float* B2h  = carvef((size_t)N_NODES * DH);
  float* A1hp = carvef((size_t)N_NODES * DH);
  float* A2hp = carvef((size_t)N_NODES * DH);
  float* C1p  = carvef((size_t)N_NODES * DH);
  float* C2p  = carvef((size_t)N_NODES * DH);
  float* hraw = carvef((size_t)N_NODES * DH);
  float* po   = carvef((size_t)N_NODES * 16);
  float* hg   = carvef(NGRAPH * 128);
  float* estats = carvef(256);
  float* hstats = carvef(256);
  float* ss_e   = carvef(256);
  float* ss_h   = carvef(256);

  unsigned short* ubase = (unsigned short*)(fbase + fo);
  unsigned short* ef_bf  = ubase;
  unsigned short* hat_bf = ubase + (size_t)N_EDGES * DH;
  int* ibase = (int*)(ubase + 2 * (size_t)N_EDGES * DH);
  int* deg       = ibase;
  int* row_start = deg + N_NODES;
  int* cursor    = row_start + (N_NODES + 3);
  int* eidx      = cursor + N_NODES;

  dim3 b256(256);

  // --- embeddings ---
  embed_nodes_k<<<dim3((N_NODES * 32 + 255) / 256), b256, 0, stream>>>(h_atoms, W_emb_h, h, N_NODES);
  embed_edges_bf<<<dim3((N_EDGES * 32 + 255) / 256), b256, 0, stream>>>(e_bonds, W_emb_e, ef_bf, N_EDGES);
  gemm_k<0><<<dim3(N_NODES / 64), b256, 0, stream>>>(
      p_in, 16, nullptr, 0, W_emb_p, b_emb_p, pc, nullptr, 0.f, NPG);

  // --- CSR over dst ---
  hipMemsetAsync(deg, 0, N_NODES * sizeof(int), stream);
  hist_k<<<dim3((N_EDGES + 255) / 256), b256, 0, stream>>>(dstI, deg, N_EDGES);
  scan_k<<<dim3(1), dim3(1024), 0, stream>>>(deg, row_start, cursor, N_NODES);
  fill_k<<<dim3((N_EDGES + 255) / 256), b256, 0, stream>>>(dstI, cursor, eidx, N_EDGES);

  // --- layers ---
  for (int l = 0; l < NLAYERS; ++l) {
    const float* b1w = B1_w + (size_t)l * 128 * 128; const float* b1b = B1_b + l * 128;
    const float* b2w = B2_w + (size_t)l * 128 * 128; const float* b2b = B2_b + l * 128;
    const float* b3w = B3_w + (size_t)l * 128 * 128; const float* b3b = B3_b + l * 128;
    const float* a1w = A1_w + (size_t)l * 256 * 128; const float* a1b = A1_b + l * 128;
    const float* a2w = A2_w + (size_t)l * 256 * 128; const float* a2b = A2_b + l * 128;
    const float* c1w = C1_w + (size_t)l * 128 * 128; const float* c1b = C1_b + l * 128;
    const float* c2w = C2_w + (size_t)l * 128 * 128; const float* c2b = C2_b + l * 128;

    gemm_k<0><<<dim3(N_NODES / 64), b256, 0, stream>>>(
        h, 128, nullptr, 0, b1w, b1b, B1h, nullptr, 0.f, NPG);
    gemm_k<0><<<dim3(N_NODES / 64), b256, 0, stream>>>(
        h, 128, nullptr, 0, b2w, b2b, B2h, nullptr, 0.f, NPG);

    hipMemsetAsync(estats, 0, 256 * sizeof(float), stream);
    gemm_edge_gate<<<dim3(N_EDGES / 64), b256, 0, stream>>>(
        ef_bf, b3w, b3b, hat_bf, srcI, dstI, B1h, B2h, estats);
    bn_finalize<<<dim3(1), dim3(128), 0, stream>>>(
        estats, bn_e_g + l * 128, bn_e_b + l * 128, 1.f / N_EDGES, ss_e);

    gemm_k<0><<<dim3(N_NODES / 64), b256, 0, stream>>>(
        h, 128, pc, 128, a1w, a1b, A1hp, nullptr, 0.f, NPG);
    gemm_k<0><<<dim3(N_NODES / 64), b256, 0, stream>>>(
        h, 128, pc, 128, a2w, a2b, A2hp, nullptr, 0.f, NPG);
    gemm_k<0><<<dim3(N_NODES / 64), b256, 0, stream>>>(
        pc, 128, nullptr, 0, c1w, c1b, C1p, nullptr, 0.f, NPG);
    gemm_k<0><<<dim3(N_NODES / 64), b256, 0, stream>>>(
        pc, 128, nullptr, 0, c2w, c2b, C2p, nullptr, 0.f, NPG);

    gate_agg<<<dim3(N_NODES), dim3(128), 0, stream>>>(
        hat_bf, row_start, eidx, srcI, A1hp, A2hp, C1p, C2p, hraw, pc);

    hipMemsetAsync(hstats, 0, 256 * sizeof(float), stream);
    col_stats<<<dim3(128), dim3(128), 0, stream>>>(hraw, hstats, N_NODES / 128);
    bn_finalize<<<dim3(1), dim3(128), 0, stream>>>(
        hstats, bn_h_g + l * 128, bn_h_b + l * 128, 1.f / N_NODES, ss_h);

    apply_bn_relu_res_f32<<<dim3(N_NODES * 32 / 256), b256, 0, stream>>>(
        h, hraw, ss_h, N_NODES * 32);
    apply_bn_relu_res_bf<<<dim3(N_EDGES * 16 / 256), b256, 0, stream>>>(
        ef_bf, hat_bf, ss_e, N_EDGES * 16);
  }

  // --- PE output head ---
  po_gemm<<<dim3(N_NODES / 16), b256, 0, stream>>>(pc, p_out_w, p_out_b, po);
  pe_norm<<<dim3(NGRAPH), b256, 0, stream>>>(po);

  hipMemsetAsync(hg, 0, NGRAPH * 128 * sizeof(float), stream);
  gemm_k<2><<<dim3(N_NODES / 64), b256, 0, stream>>>(
      h, 128, po, 16, Whp_w, Whp_b, nullptr, hg, 1.f / NPG, NPG);

  mlp_head<<<dim3(1), b256, 0, stream>>>(
      hg, mlp_w0, mlp_b0, mlp_w1, mlp_b1, mlp_w2, mlp_b2, (float*)d_out);
}

// Round 4
// 3569.903 us; speedup vs baseline: 1.9452x; 1.9452x over previous
//
#include <hip/hip_runtime.h>
#include <math.h>

#define N_NODES 40960
#define N_EDGES 655360
#define NPG     640
#define NGRAPH  64
#define DH      128
#define NLAYERS 4
#define GATE_EPS 1e-6f
#define BN_EPS   1e-5f

// Static device scratch pool (module-load allocated; graph-capture safe).
// d_ws proved too small in rounds 1-2 (< 509 MB).
#define POOL_BYTES 560000000ull
__device__ __attribute__((aligned(256))) unsigned char g_pool[POOL_BYTES];

using short8  = __attribute__((ext_vector_type(8))) short;
using float4v = __attribute__((ext_vector_type(4))) float;

static __device__ __forceinline__ float sigmoidf_(float x) {
  return 1.f / (1.f + __expf(-x));
}
static __device__ __forceinline__ unsigned short f2bf(float f) {
  unsigned int u = __float_as_uint(f);
  unsigned int r = 0x7FFFu + ((u >> 16) & 1u);
  return (unsigned short)((u + r) >> 16);
}
static __device__ __forceinline__ float bf2f(unsigned short h) {
  return __uint_as_float(((unsigned int)h) << 16);
}

// ---------------------------------------------------------------------------
// MFMA GEMM: out[M,128] = A_bf16[M rows, Ktot cols at col_off within lda] @ Wt + bias
// Wt is bf16 TRANSPOSED: Wt[n*Ktot + k]  (n = out col 0..127)
// Block 256 thr = 4 waves, tile 64 rows x 128 cols. mfma_f32_16x16x32_bf16:
//   A frag: lane holds A[m=lane&15][k=quad*8+j]; B frag: B[k=quad*8+j][n=lane&15]
//   D frag: col=lane&15, row=quad*4+reg   (m89/m120-verified mappings)
// MODE 0: fp32 store. MODE 1: edge-gate epilogue (+G1[src]+G2[dst], bf16 store,
//         column sum/sumsq atomics into stats).
// ---------------------------------------------------------------------------
template <int MODE>
__global__ __launch_bounds__(256)
void mgemm(const unsigned short* __restrict__ Abf, int lda, int col_off, int Ktot,
           const unsigned short* __restrict__ Wt,
           const float* __restrict__ bias,
           float* __restrict__ out_f,
           unsigned short* __restrict__ out_bf,
           const int* __restrict__ srcI, const int* __restrict__ dstI,
           const float* __restrict__ G1, const float* __restrict__ G2,
           float* __restrict__ stats)
{
  __shared__ unsigned short As[64][136];   // +8 pad: 2-way-free bank pattern
  __shared__ unsigned short Ws[128][136];

  const int t    = threadIdx.x;
  const int w    = t >> 6;
  const int lane = t & 63;
  const int quad = lane >> 4;
  const int l16  = lane & 15;
  const size_t row0 = (size_t)blockIdx.x * 64;

  float4v acc[8];
#pragma unroll
  for (int j = 0; j < 8; ++j) acc[j] = (float4v){0.f, 0.f, 0.f, 0.f};

  for (int kc = 0; kc < Ktot; kc += 128) {
    if (kc) __syncthreads();
#pragma unroll
    for (int i = 0; i < 4; ++i) {           // A: 64x128 bf16 = 16 KB
      int flat = i * 256 + t;
      int r = flat >> 4, g = flat & 15;
      *reinterpret_cast<uint4*>(&As[r][g * 8]) =
          *reinterpret_cast<const uint4*>(&Abf[(row0 + r) * lda + col_off + kc + g * 8]);
    }
#pragma unroll
    for (int i = 0; i < 8; ++i) {           // Wt: 128x128 bf16 = 32 KB
      int flat = i * 256 + t;
      int n = flat >> 4, g = flat & 15;
      *reinterpret_cast<uint4*>(&Ws[n][g * 8]) =
          *reinterpret_cast<const uint4*>(&Wt[(size_t)n * Ktot + kc + g * 8]);
    }
    __syncthreads();

#pragma unroll
    for (int ks = 0; ks < 4; ++ks) {
      short8 a = *reinterpret_cast<const short8*>(&As[w * 16 + l16][ks * 32 + quad * 8]);
#pragma unroll
      for (int j = 0; j < 8; ++j) {
        short8 b = *reinterpret_cast<const short8*>(&Ws[j * 16 + l16][ks * 32 + quad * 8]);
        acc[j] = __builtin_amdgcn_mfma_f32_16x16x32_bf16(a, b, acc[j], 0, 0, 0);
      }
    }
  }

  if (MODE == 0) {
#pragma unroll
    for (int j = 0; j < 8; ++j) {
      int col = j * 16 + l16;
      float bcol = bias[col];
#pragma unroll
      for (int r = 0; r < 4; ++r) {
        size_t row = row0 + w * 16 + quad * 4 + r;
        out_f[row * 128 + col] = acc[j][r] + bcol;
      }
    }
  } else {
    int rowbase = (int)row0 + w * 16 + quad * 4;
    int sI[4], dI[4];
#pragma unroll
    for (int r = 0; r < 4; ++r) { sI[r] = srcI[rowbase + r]; dI[r] = dstI[rowbase + r]; }
    float cs[8], cq[8];
#pragma unroll
    for (int j = 0; j < 8; ++j) {
      int col = j * 16 + l16;
      float bcol = bias[col];
      float s = 0.f, q = 0.f;
#pragma unroll
      for (int r = 0; r < 4; ++r) {
        float v = acc[j][r] + bcol + G1[(size_t)sI[r] * 128 + col]
                                   + G2[(size_t)dI[r] * 128 + col];
        unsigned short hv = f2bf(v);
        out_bf[(size_t)(rowbase + r) * 128 + col] = hv;
        float vr = bf2f(hv);
        s += vr; q += vr * vr;
      }
      cs[j] = s; cq[j] = q;
    }
#pragma unroll
    for (int j = 0; j < 8; ++j) {
      cs[j] += __shfl_xor(cs[j], 16); cs[j] += __shfl_xor(cs[j], 32);
      cq[j] += __shfl_xor(cq[j], 16); cq[j] += __shfl_xor(cq[j], 32);
    }
    {
      __shared__ float reds[4][128];
      __shared__ float redq[4][128];
      if (quad == 0) {
#pragma unroll
        for (int j = 0; j < 8; ++j) {
          reds[w][j * 16 + l16] = cs[j];
          redq[w][j * 16 + l16] = cq[j];
        }
      }
      __syncthreads();
      if (t < 128) {
        atomicAdd(&stats[t], reds[0][t] + reds[1][t] + reds[2][t] + reds[3][t]);
      } else if (t < 256) {
        int c = t - 128;
        atomicAdd(&stats[128 + c], redq[0][c] + redq[1][c] + redq[2][c] + redq[3][c]);
      }
    }
  }
}

// ---------------------------------------------------------------------------
// One-time per call: all layer weights -> bf16 transposed Wt[n][k].
// Layout per layer (ushort offsets): B1@0 B2@16384 B3@32768 A1@49152 A2@81920
// C1@114688 C2@131072; layer stride 147456.
// ---------------------------------------------------------------------------
__global__ void prep_weights(const float* __restrict__ B1, const float* __restrict__ B2,
                             const float* __restrict__ B3, const float* __restrict__ A1,
                             const float* __restrict__ A2, const float* __restrict__ C1,
                             const float* __restrict__ C2, unsigned short* __restrict__ Wt)
{
  int idx = blockIdx.x * 256 + threadIdx.x;
  if (idx >= 4 * 147456) return;
  int layer = idx / 147456;
  int o = idx - layer * 147456;
  const float* src; int K, local;
  if (o < 16384)       { src = B1 + layer * 16384; local = o;          K = 128; }
  else if (o < 32768)  { src = B2 + layer * 16384; local = o - 16384;  K = 128; }
  else if (o < 49152)  { src = B3 + layer * 16384; local = o - 32768;  K = 128; }
  else if (o < 81920)  { src = A1 + layer * 32768; local = o - 49152;  K = 256; }
  else if (o < 114688) { src = A2 + layer * 32768; local = o - 81920;  K = 256; }
  else if (o < 131072) { src = C1 + layer * 16384; local = o - 114688; K = 128; }
  else                 { src = C2 + layer * 16384; local = o - 131072; K = 128; }
  int n = local / K, k = local - n * K;
  Wt[idx] = f2bf(src[k * 128 + n]);
}

// hp_bf[n][0:128]=bf16(h), [128:256]=bf16(pc). N*64 threads, 8B stores.
__global__ void convert_hp(const float* __restrict__ h, const float* __restrict__ pc,
                           unsigned short* __restrict__ hp)
{
  int t = blockIdx.x * 256 + threadIdx.x;
  if (t >= N_NODES * 64) return;
  int n = t >> 6, part = t & 63;
  float4 v = (part < 32) ? reinterpret_cast<const float4*>(h)[n * 32 + part]
                         : reinterpret_cast<const float4*>(pc)[n * 32 + (part - 32)];
  ushort4 o;
  o.x = f2bf(v.x); o.y = f2bf(v.y); o.z = f2bf(v.z); o.w = f2bf(v.w);
  reinterpret_cast<ushort4*>(hp)[n * 64 + part] = o;
}

// ---------------------------------------------------------------------------
__global__ void embed_nodes_k(const int* __restrict__ idx, const float* __restrict__ table,
                              float* __restrict__ out, int M)
{
  int t = blockIdx.x * 256 + threadIdx.x;
  if (t < M * 32) {
    int r = t >> 5, c = t & 31;
    reinterpret_cast<float4*>(out)[t] =
        reinterpret_cast<const float4*>(table)[idx[r] * 32 + c];
  }
}

__global__ void embed_edges_bf(const int* __restrict__ idx, const float* __restrict__ table,
                               unsigned short* __restrict__ out, int M)
{
  int t = blockIdx.x * 256 + threadIdx.x;
  if (t < M * 32) {
    int r = t >> 5, c = t & 31;
    float4 v = reinterpret_cast<const float4*>(table)[idx[r] * 32 + c];
    ushort4 o;
    o.x = f2bf(v.x); o.y = f2bf(v.y); o.z = f2bf(v.z); o.w = f2bf(v.w);
    reinterpret_cast<ushort4*>(out)[t] = o;
  }
}

// ---------------------------------------------------------------------------
// fp32 GEMM (kept for pc-embedding K=16 and Whp graph-mean MODE 2)
// ---------------------------------------------------------------------------
template <int MODE>
__global__ __launch_bounds__(256)
void gemm_k(const float* __restrict__ Xa, int Ka,
            const float* __restrict__ Xb, int Kb,
            const float* __restrict__ W,
            const float* __restrict__ bias,
            float* __restrict__ out,
            float* __restrict__ hg, float inv_nodes, int npg)
{
  __shared__ float Xs[16][68];
  __shared__ float Ws[16][128];
  __shared__ float red[8][128];

  const int t  = threadIdx.x;
  const int ty = t >> 5;
  const int tx = t & 31;
  const int row0 = blockIdx.x * 64;
  const int K = Ka + Kb;

  float acc[8][4];
#pragma unroll
  for (int i = 0; i < 8; ++i)
#pragma unroll
    for (int j = 0; j < 4; ++j) acc[i][j] = 0.f;

  const int xr = t >> 2;
  const int xk = (t & 3) << 2;
  const int wr = t >> 5;
  const int wc = tx << 2;

  for (int kk = 0; kk < K; kk += 16) {
    const float* xbase; int ldk, kloc;
    if (kk < Ka) { xbase = Xa; ldk = Ka; kloc = kk; }
    else         { xbase = Xb; ldk = Kb; kloc = kk - Ka; }
    float4 xv = *reinterpret_cast<const float4*>(
        &xbase[(size_t)(row0 + xr) * ldk + kloc + xk]);
    Xs[xk + 0][xr] = xv.x; Xs[xk + 1][xr] = xv.y;
    Xs[xk + 2][xr] = xv.z; Xs[xk + 3][xr] = xv.w;

    float4 wv0 = *reinterpret_cast<const float4*>(&W[(size_t)(kk + wr) * 128 + wc]);
    float4 wv1 = *reinterpret_cast<const float4*>(&W[(size_t)(kk + wr + 8) * 128 + wc]);
    *reinterpret_cast<float4*>(&Ws[wr][wc])     = wv0;
    *reinterpret_cast<float4*>(&Ws[wr + 8][wc]) = wv1;
    __syncthreads();

#pragma unroll
    for (int k = 0; k < 16; ++k) {
      float4 b4 = *reinterpret_cast<const float4*>(&Ws[k][wc]);
      float4 a0 = *reinterpret_cast<const float4*>(&Xs[k][ty << 3]);
      float4 a1 = *reinterpret_cast<const float4*>(&Xs[k][(ty << 3) + 4]);
      float a[8] = {a0.x, a0.y, a0.z, a0.w, a1.x, a1.y, a1.z, a1.w};
      float b[4] = {b4.x, b4.y, b4.z, b4.w};
#pragma unroll
      for (int i = 0; i < 8; ++i) {
        acc[i][0] += a[i] * b[0];
        acc[i][1] += a[i] * b[1];
        acc[i][2] += a[i] * b[2];
        acc[i][3] += a[i] * b[3];
      }
    }
    __syncthreads();
  }

  float4 bb = *reinterpret_cast<const float4*>(&bias[wc]);
  float bv[4] = {bb.x, bb.y, bb.z, bb.w};

  if (MODE == 0) {
#pragma unroll
    for (int i = 0; i < 8; ++i) {
      int r = row0 + (ty << 3) + i;
      float4 ov;
      ov.x = acc[i][0] + bv[0]; ov.y = acc[i][1] + bv[1];
      ov.z = acc[i][2] + bv[2]; ov.w = acc[i][3] + bv[3];
      *reinterpret_cast<float4*>(&out[(size_t)r * 128 + wc]) = ov;
    }
  } else {
    float csum[4] = {0, 0, 0, 0};
#pragma unroll
    for (int i = 0; i < 8; ++i) {
      csum[0] += acc[i][0]; csum[1] += acc[i][1];
      csum[2] += acc[i][2]; csum[3] += acc[i][3];
    }
#pragma unroll
    for (int j = 0; j < 4; ++j) red[ty][wc + j] = csum[j];
    __syncthreads();
    if (ty == 0) {
      int g = row0 / npg;
#pragma unroll
      for (int j = 0; j < 4; ++j) {
        float s = 0;
#pragma unroll
        for (int q = 0; q < 8; ++q) s += red[q][wc + j];
        atomicAdd(&hg[(size_t)g * 128 + wc + j], (s + 64.f * bv[j]) * inv_nodes);
      }
    }
  }
}

// ---------------------------------------------------------------------------
// CSR build over dst
// ---------------------------------------------------------------------------
__global__ void hist_k(const int* __restrict__ dstI, int* __restrict__ deg, int E)
{
  int e = blockIdx.x * 256 + threadIdx.x;
  if (e < E) atomicAdd(&deg[dstI[e]], 1);
}

__global__ void scan_k(const int* __restrict__ deg, int* __restrict__ row_start,
                       int* __restrict__ cursor, int n)
{
  __shared__ int buf[1024];
  __shared__ int carry;
  int t = threadIdx.x;
  if (t == 0) carry = 0;
  __syncthreads();
  for (int b0 = 0; b0 < n; b0 += 1024) {
    int v = (b0 + t < n) ? deg[b0 + t] : 0;
    buf[t] = v;
    __syncthreads();
    for (int off = 1; off < 1024; off <<= 1) {
      int add = (t >= off) ? buf[t - off] : 0;
      __syncthreads();
      buf[t] += add;
      __syncthreads();
    }
    int incl = buf[t];
    int excl = carry + incl - v;
    if (b0 + t < n) { row_start[b0 + t] = excl; cursor[b0 + t] = excl; }
    __syncthreads();
    if (t == 1023) carry += incl;
    __syncthreads();
  }
  if (t == 0) row_start[n] = carry;
}

__global__ void fill_k(const int* __restrict__ dstI, int* __restrict__ cursor,
                       int* __restrict__ eidx, int E)
{
  int e = blockIdx.x * 256 + threadIdx.x;
  if (e < E) {
    int p = atomicAdd(&cursor[dstI[e]], 1);
    eidx[p] = e;
  }
}

// ---------------------------------------------------------------------------
// Gate normalization + aggregation: one WAVE per node, 2 cols/lane.
// ---------------------------------------------------------------------------
__global__ __launch_bounds__(256)
void gate_agg2(const unsigned short* __restrict__ hat, const int* __restrict__ row_start,
               const int* __restrict__ eidx, const int* __restrict__ srcI,
               const float* __restrict__ A1hp, const float* __restrict__ A2hp,
               const float* __restrict__ C1p, const float* __restrict__ C2p,
               float* __restrict__ hraw, float* __restrict__ pc)
{
  int t = threadIdx.x;
  int node = blockIdx.x * 4 + (t >> 6);
  int lane = t & 63;
  int c = lane * 2;
  int beg = row_start[node], end = row_start[node + 1];

  float s0 = 0.f, s1 = 0.f;
  for (int ii = beg; ii < end; ++ii) {
    int e = eidx[ii];
    ushort2 hv = *reinterpret_cast<const ushort2*>(&hat[(size_t)e * 128 + c]);
    s0 += sigmoidf_(bf2f(hv.x));
    s1 += sigmoidf_(bf2f(hv.y));
  }
  float inv0 = 1.f / (s0 + GATE_EPS);
  float inv1 = 1.f / (s1 + GATE_EPS);

  float ha0 = 0.f, ha1 = 0.f, pa0 = 0.f, pa1 = 0.f;
  for (int ii = beg; ii < end; ++ii) {
    int e = eidx[ii];
    int s = srcI[e];
    ushort2 hv = *reinterpret_cast<const ushort2*>(&hat[(size_t)e * 128 + c]);
    float w0 = sigmoidf_(bf2f(hv.x)) * inv0;
    float w1 = sigmoidf_(bf2f(hv.y)) * inv1;
    float2 a2 = *reinterpret_cast<const float2*>(&A2hp[(size_t)s * 128 + c]);
    float2 c2 = *reinterpret_cast<const float2*>(&C2p[(size_t)s * 128 + c]);
    ha0 += w0 * a2.x; ha1 += w1 * a2.y;
    pa0 += w0 * c2.x; pa1 += w1 * c2.y;
  }
  size_t ix = (size_t)node * 128 + c;
  float2 a1 = *reinterpret_cast<const float2*>(&A1hp[ix]);
  float2 c1 = *reinterpret_cast<const float2*>(&C1p[ix]);
  float2 hv; hv.x = a1.x + ha0; hv.y = a1.y + ha1;
  *reinterpret_cast<float2*>(&hraw[ix]) = hv;
  float2 pv = *reinterpret_cast<float2*>(&pc[ix]);
  pv.x += tanhf(c1.x + pa0);
  pv.y += tanhf(c1.y + pa1);
  *reinterpret_cast<float2*>(&pc[ix]) = pv;
}

// ---------------------------------------------------------------------------
__global__ __launch_bounds__(128)
void col_stats(const float* __restrict__ x, float* __restrict__ stats, int rowsPerBlock)
{
  int d = threadIdx.x;
  size_t r0 = (size_t)blockIdx.x * rowsPerBlock;
  float s = 0.f, q = 0.f;
  for (int i = 0; i < rowsPerBlock; ++i) {
    float v = x[(r0 + i) * 128 + d];
    s += v; q += v * v;
  }
  atomicAdd(&stats[d], s);
  atomicAdd(&stats[128 + d], q);
}

__global__ void bn_finalize(const float* __restrict__ stats, const float* __restrict__ g,
                            const float* __restrict__ b, float invM, float* __restrict__ ss)
{
  int c = threadIdx.x;
  float m = stats[c] * invM;
  float v = stats[128 + c] * invM - m * m;
  float A = rsqrtf(v + BN_EPS) * g[c];
  ss[c] = A;
  ss[128 + c] = b[c] - m * A;
}

__global__ void apply_bn_relu_res_f32(float* __restrict__ dest, const float* __restrict__ xraw,
                                      const float* __restrict__ ss, int total4)
{
  int t = blockIdx.x * 256 + threadIdx.x;
  if (t >= total4) return;
  int c4 = t & 31;
  float4 x = reinterpret_cast<const float4*>(xraw)[t];
  float4 A = reinterpret_cast<const float4*>(ss)[c4];
  float4 B = reinterpret_cast<const float4*>(ss + 128)[c4];
  float4 dv = reinterpret_cast<float4*>(dest)[t];
  dv.x += fmaxf(x.x * A.x + B.x, 0.f);
  dv.y += fmaxf(x.y * A.y + B.y, 0.f);
  dv.z += fmaxf(x.z * A.z + B.z, 0.f);
  dv.w += fmaxf(x.w * A.w + B.w, 0.f);
  reinterpret_cast<float4*>(dest)[t] = dv;
}

__global__ void apply_bn_relu_res_bf(unsigned short* __restrict__ ef,
                                     const unsigned short* __restrict__ hat,
                                     const float* __restrict__ ss, int total8)
{
  int t = blockIdx.x * 256 + threadIdx.x;
  if (t >= total8) return;
  int c8 = t & 15;
  uint4 xb = reinterpret_cast<const uint4*>(hat)[t];
  uint4 eb = reinterpret_cast<const uint4*>(ef)[t];
  float4 A0 = reinterpret_cast<const float4*>(ss)[c8 * 2];
  float4 A1 = reinterpret_cast<const float4*>(ss)[c8 * 2 + 1];
  float4 B0 = reinterpret_cast<const float4*>(ss + 128)[c8 * 2];
  float4 B1 = reinterpret_cast<const float4*>(ss + 128)[c8 * 2 + 1];
  float Av[8] = {A0.x, A0.y, A0.z, A0.w, A1.x, A1.y, A1.z, A1.w};
  float Bv[8] = {B0.x, B0.y, B0.z, B0.w, B1.x, B1.y, B1.z, B1.w};
  unsigned int xw[4] = {xb.x, xb.y, xb.z, xb.w};
  unsigned int ew[4] = {eb.x, eb.y, eb.z, eb.w};
  uint4 ov;
  unsigned int res[4];
#pragma unroll
  for (int i = 0; i < 4; ++i) {
    float xlo = bf2f((unsigned short)(xw[i] & 0xffffu));
    float xhi = bf2f((unsigned short)(xw[i] >> 16));
    float elo = bf2f((unsigned short)(ew[i] & 0xffffu));
    float ehi = bf2f((unsigned short)(ew[i] >> 16));
    float ylo = elo + fmaxf(xlo * Av[2 * i] + Bv[2 * i], 0.f);
    float yhi = ehi + fmaxf(xhi * Av[2 * i + 1] + Bv[2 * i + 1], 0.f);
    res[i] = (unsigned int)f2bf(ylo) | ((unsigned int)f2bf(yhi) << 16);
  }
  ov.x = res[0]; ov.y = res[1]; ov.z = res[2]; ov.w = res[3];
  reinterpret_cast<uint4*>(ef)[t] = ov;
}

// ---------------------------------------------------------------------------
__global__ __launch_bounds__(256)
void po_gemm(const float* __restrict__ pc, const float* __restrict__ w,
             const float* __restrict__ b, float* __restrict__ po)
{
  __shared__ float pcs[16][128];
  __shared__ float wl[128][16];
  int t = threadIdx.x;
  int n0 = blockIdx.x * 16;
  for (int i = t; i < 512; i += 256) {
    int r = i >> 5, c = (i & 31) << 2;
    *reinterpret_cast<float4*>(&pcs[r][c]) =
        *reinterpret_cast<const float4*>(&pc[(size_t)(n0 + r) * 128 + c]);
  }
  for (int i = t; i < 512; i += 256) {
    int r = i >> 2, c = (i & 3) << 2;
    *reinterpret_cast<float4*>(&wl[r][c]) =
        *reinterpret_cast<const float4*>(&w[r * 16 + c]);
  }
  __syncthreads();
  int i = t >> 4, j = t & 15;
  float acc = b[j];
  for (int k = 0; k < 128; ++k) acc += pcs[i][k] * wl[k][j];
  po[(size_t)(n0 + i) * 16 + j] = acc;
}

__global__ __launch_bounds__(256)
void pe_norm(float* __restrict__ po)
{
  int g = blockIdx.x;
  int t = threadIdx.x;
  int j = t & 15, grp = t >> 4;
  __shared__ float red[16][16];
  __shared__ float mean_s[16];
  __shared__ float nrm_s[16];
  size_t bse = (size_t)g * NPG * 16;
  float s = 0.f;
  for (int i = grp; i < NPG; i += 16) s += po[bse + i * 16 + j];
  red[grp][j] = s;
  __syncthreads();
  if (grp == 0) {
    float m = 0.f;
    for (int q = 0; q < 16; ++q) m += red[q][j];
    mean_s[j] = m / NPG;
  }
  __syncthreads();
  float m = mean_s[j];
  float q2 = 0.f;
  for (int i = grp; i < NPG; i += 16) {
    float c = po[bse + i * 16 + j] - m;
    q2 += c * c;
  }
  red[grp][j] = q2;
  __syncthreads();
  if (grp == 0) {
    float v = 0.f;
    for (int q = 0; q < 16; ++q) v += red[q][j];
    nrm_s[j] = sqrtf(v);
  }
  __syncthreads();
  float inv = 1.f / nrm_s[j];
  for (int i = grp; i < NPG; i += 16) {
    size_t ix = bse + i * 16 + j;
    po[ix] = (po[ix] - m) * inv;
  }
}

__global__ __launch_bounds__(256)
void mlp_head(const float* __restrict__ hg,
              const float* __restrict__ w0, const float* __restrict__ b0,
              const float* __restrict__ w1, const float* __restrict__ b1,
              const float* __restrict__ w2, const float* __restrict__ b2,
              float* __restrict__ out)
{
  __shared__ float hs[64 * 128];
  __shared__ float y0[64 * 64];
  __shared__ float y1[64 * 32];
  int t = threadIdx.x;
  for (int i = t; i < 64 * 128 / 4; i += 256)
    reinterpret_cast<float4*>(hs)[i] = reinterpret_cast<const float4*>(hg)[i];
  __syncthreads();
  for (int o = t; o < 64 * 64; o += 256) {
    int i = o >> 6, j = o & 63;
    float a = b0[j];
    for (int k = 0; k < 128; ++k) a += hs[i * 128 + k] * w0[k * 64 + j];
    y0[o] = fmaxf(a, 0.f);
  }
  __syncthreads();
  for (int o = t; o < 64 * 32; o += 256) {
    int i = o >> 5, j = o & 31;
    float a = b1[j];
    for (int k = 0; k < 64; ++k) a += y0[i * 64 + k] * w1[k * 32 + j];
    y1[o] = fmaxf(a, 0.f);
  }
  __syncthreads();
  if (t < 64) {
    float a = b2[0];
    for (int k = 0; k < 32; ++k) a += y1[t * 32 + k] * w2[k];
    out[t] = a;
  }
}

__global__ void fill_sentinel(float* out, int n, float v)
{
  int t = blockIdx.x * 256 + threadIdx.x;
  if (t < n) out[t] = v;
}

// ---------------------------------------------------------------------------
extern "C" void kernel_launch(void* const* d_in, const int* in_sizes, int n_in,
                              void* d_out, int out_size, void* d_ws, size_t ws_size,
                              hipStream_t stream)
{
  const int*   h_atoms = (const int*)d_in[0];
  const int*   e_bonds = (const int*)d_in[1];
  const int*   srcI    = (const int*)d_in[2];
  const int*   dstI    = (const int*)d_in[3];
  const float* p_in    = (const float*)d_in[5];
  const float* W_emb_h = (const float*)d_in[6];
  const float* W_emb_p = (const float*)d_in[7];
  const float* b_emb_p = (const float*)d_in[8];
  const float* W_emb_e = (const float*)d_in[9];
  const float* A1_w = (const float*)d_in[10];
  const float* A1_b = (const float*)d_in[11];
  const float* A2_w = (const float*)d_in[12];
  const float* A2_b = (const float*)d_in[13];
  const float* B1_w = (const float*)d_in[14];
  const float* B1_b = (const float*)d_in[15];
  const float* B2_w = (const float*)d_in[16];
  const float* B2_b = (const float*)d_in[17];
  const float* B3_w = (const float*)d_in[18];
  const float* B3_b = (const float*)d_in[19];
  const float* C1_w = (const float*)d_in[20];
  const float* C1_b = (const float*)d_in[21];
  const float* C2_w = (const float*)d_in[22];
  const float* C2_b = (const float*)d_in[23];
  const float* bn_h_g = (const float*)d_in[24];
  const float* bn_h_b = (const float*)d_in[25];
  const float* bn_e_g = (const float*)d_in[26];
  const float* bn_e_b = (const float*)d_in[27];
  const float* p_out_w = (const float*)d_in[28];
  const float* p_out_b = (const float*)d_in[29];
  const float* Whp_w   = (const float*)d_in[30];
  const float* Whp_b   = (const float*)d_in[31];
  const float* mlp_w0  = (const float*)d_in[32];
  const float* mlp_b0  = (const float*)d_in[33];
  const float* mlp_w1  = (const float*)d_in[34];
  const float* mlp_b1  = (const float*)d_in[35];
  const float* mlp_w2  = (const float*)d_in[36];
  const float* mlp_b2  = (const float*)d_in[37];

  static void* pool_ptr = nullptr;
  if (!pool_ptr) {
    if (hipGetSymbolAddress(&pool_ptr, HIP_SYMBOL(g_pool)) != hipSuccess || !pool_ptr) {
      fill_sentinel<<<dim3(1), dim3(256), 0, stream>>>((float*)d_out, out_size, 12345.0f);
      return;
    }
  }

  float* fbase = (float*)pool_ptr;
  size_t fo = 0;
  auto carvef = [&](size_t nf) { float* r = fbase + fo; fo += nf; return r; };
  float* h    = carvef((size_t)N_NODES * DH);
  float* pc   = carvef((size_t)N_NODES * DH);
  float* B1h  = carvef((size_t)N_NODES * DH);   // aliased as hraw after edge GEMM
  float* B2h  = carvef((size_t)N_NODES * DH);
  float* A1hp = carvef((size_t)N_NODES * DH);
  float* A2hp = carvef((size_t)N_NODES * DH);
  float* C1p  = carvef((size_t)N_NODES * DH);
  float* C2p  = carvef((size_t)N_NODES * DH);
  float* po   = carvef((size_t)N_NODES * 16);
  float* hg   = carvef(NGRAPH * 128);
  float* estats = carvef(256);
  float* hstats = carvef(256);
  float* ss_e   = carvef(256);
  float* ss_h   = carvef(256);
  float* hraw = B1h;

  unsigned short* ubase = (unsigned short*)(fbase + fo);
  unsigned short* ef_bf  = ubase;
  unsigned short* hat_bf = ef_bf + (size_t)N_EDGES * DH;
  unsigned short* hp_bf  = hat_bf + (size_t)N_EDGES * DH;
  unsigned short* Wt_bf  = hp_bf + (size_t)N_NODES * 256;
  int* ibase = (int*)(Wt_bf + 4 * 147456);
  int* deg       = ibase;
  int* row_start = deg + N_NODES;
  int* cursor    = row_start + (N_NODES + 3);
  int* eidx      = cursor + N_NODES;

  dim3 b256(256);

  // --- weight prep (bf16 transposed) ---
  prep_weights<<<dim3((4 * 147456 + 255) / 256), b256, 0, stream>>>(
      B1_w, B2_w, B3_w, A1_w, A2_w, C1_w, C2_w, Wt_bf);

  // --- embeddings ---
  embed_nodes_k<<<dim3((N_NODES * 32 + 255) / 256), b256, 0, stream>>>(h_atoms, W_emb_h, h, N_NODES);
  embed_edges_bf<<<dim3((N_EDGES * 32 + 255) / 256), b256, 0, stream>>>(e_bonds, W_emb_e, ef_bf, N_EDGES);
  gemm_k<0><<<dim3(N_NODES / 64), b256, 0, stream>>>(
      p_in, 16, nullptr, 0, W_emb_p, b_emb_p, pc, nullptr, 0.f, NPG);

  // --- CSR over dst ---
  hipMemsetAsync(deg, 0, N_NODES * sizeof(int), stream);
  hist_k<<<dim3((N_EDGES + 255) / 256), b256, 0, stream>>>(dstI, deg, N_EDGES);
  scan_k<<<dim3(1), dim3(1024), 0, stream>>>(deg, row_start, cursor, N_NODES);
  fill_k<<<dim3((N_EDGES + 255) / 256), b256, 0, stream>>>(dstI, cursor, eidx, N_EDGES);

  const dim3 gNode(N_NODES / 64), gEdge(N_EDGES / 64);

  // --- layers ---
  for (int l = 0; l < NLAYERS; ++l) {
    const unsigned short* WtL = Wt_bf + (size_t)l * 147456;
    const unsigned short* WtB1 = WtL;
    const unsigned short* WtB2 = WtL + 16384;
    const unsigned short* WtB3 = WtL + 32768;
    const unsigned short* WtA1 = WtL + 49152;
    const unsigned short* WtA2 = WtL + 81920;
    const unsigned short* WtC1 = WtL + 114688;
    const unsigned short* WtC2 = WtL + 131072;

    convert_hp<<<dim3(N_NODES * 64 / 256), b256, 0, stream>>>(h, pc, hp_bf);

    mgemm<0><<<gNode, b256, 0, stream>>>(hp_bf, 256, 0, 128, WtB1, B1_b + l * 128,
        B1h, nullptr, nullptr, nullptr, nullptr, nullptr, nullptr);
    mgemm<0><<<gNode, b256, 0, stream>>>(hp_bf, 256, 0, 128, WtB2, B2_b + l * 128,
        B2h, nullptr, nullptr, nullptr, nullptr, nullptr, nullptr);

    hipMemsetAsync(estats, 0, 256 * sizeof(float), stream);
    mgemm<1><<<gEdge, b256, 0, stream>>>(ef_bf, 128, 0, 128, WtB3, B3_b + l * 128,
        nullptr, hat_bf, srcI, dstI, B1h, B2h, estats);
    bn_finalize<<<dim3(1), dim3(128), 0, stream>>>(
        estats, bn_e_g + l * 128, bn_e_b + l * 128, 1.f / N_EDGES, ss_e);

    mgemm<0><<<gNode, b256, 0, stream>>>(hp_bf, 256, 0, 256, WtA1, A1_b + l * 128,
        A1hp, nullptr, nullptr, nullptr, nullptr, nullptr, nullptr);
    mgemm<0><<<gNode, b256, 0, stream>>>(hp_bf, 256, 0, 256, WtA2, A2_b + l * 128,
        A2hp, nullptr, nullptr, nullptr, nullptr, nullptr, nullptr);
    mgemm<0><<<gNode, b256, 0, stream>>>(hp_bf, 256, 128, 128, WtC1, C1_b + l * 128,
        C1p, nullptr, nullptr, nullptr, nullptr, nullptr, nullptr);
    mgemm<0><<<gNode, b256, 0, stream>>>(hp_bf, 256, 128, 128, WtC2, C2_b + l * 128,
        C2p, nullptr, nullptr, nullptr, nullptr, nullptr, nullptr);

    gate_agg2<<<dim3(N_NODES / 4), b256, 0, stream>>>(
        hat_bf, row_start, eidx, srcI, A1hp, A2hp, C1p, C2p, hraw, pc);

    hipMemsetAsync(hstats, 0, 256 * sizeof(float), stream);
    col_stats<<<dim3(128), dim3(128), 0, stream>>>(hraw, hstats, N_NODES / 128);
    bn_finalize<<<dim3(1), dim3(128), 0, stream>>>(
        hstats, bn_h_g + l * 128, bn_h_b + l * 128, 1.f / N_NODES, ss_h);

    apply_bn_relu_res_f32<<<dim3(N_NODES * 32 / 256), b256, 0, stream>>>(
        h, hraw, ss_h, N_NODES * 32);
    apply_bn_relu_res_bf<<<dim3(N_EDGES * 16 / 256), b256, 0, stream>>>(
        ef_bf, hat_bf, ss_e, N_EDGES * 16);
  }

  // --- PE output head ---
  po_gemm<<<dim3(N_NODES / 16), b256, 0, stream>>>(pc, p_out_w, p_out_b, po);
  pe_norm<<<dim3(NGRAPH), b256, 0, stream>>>(po);

  hipMemsetAsync(hg, 0, NGRAPH * 128 * sizeof(float), stream);
  gemm_k<2><<<dim3(N_NODES / 64), b256, 0, stream>>>(
      h, 128, po, 16, Whp_w, Whp_b, nullptr, hg, 1.f / NPG, NPG);

  mlp_head<<<dim3(1), b256, 0, stream>>>(
      hg, mlp_w0, mlp_b0, mlp_w1, mlp_b1, mlp_w2, mlp_b2, (float*)d_out);
}